// Round 21
// baseline (321.424 us; speedup 1.0000x reference)
//
#include <hip/hip_runtime.h>
#include <hip/hip_bf16.h>
#include <math.h>
#include <stdint.h>

// Problem constants
#define CCH   192      // channels
#define HWD   224      // H = W = 224
#define NWIN  8192     // 8 * 32 * 32 windows
#define NPIX  49       // 7*7 pixels per window
#define KDIM  192      // GEMM1 K
#define NHEAD 6
#define ROWB  (KDIM * 2)       // 384 bytes per LDS row
#define NBLK  (NWIN / 2)       // 4096 blocks, 2 windows each
#define WSZ   (NPIX * KDIM * 2)  // 18816 B per tile buffer
#define X0O   0
#define X1O   (1 * WSZ)
#define Q0O   (2 * WSZ)
#define K0O   (3 * WSZ)
#define Q1O   (4 * WSZ)
#define K1O   (5 * WSZ)
#define LDSSZ (6 * WSZ)        // 112896 B dynamic LDS (R19 proved launchable)
#define MULQ  0.2550348616845977f   // 32^-0.5 * log2(e), folded into W_q/b_q

typedef __bf16 bf16x8 __attribute__((ext_vector_type(8)));
typedef __bf16 bf16x2 __attribute__((ext_vector_type(2)));
typedef float  f32x4  __attribute__((ext_vector_type(4)));

// Convert W (384x192 f32) to bf16 pre-swizzled into MFMA B-fragment order,
// with scale*log2e pre-folded into the q half. Bias (scaled) at wbf+73728.
__global__ void wconv_kernel(const float* __restrict__ w,
                             const float* __restrict__ bq,
                             uint16_t* __restrict__ wbf) {
    int o = blockIdx.x * 256 + threadIdx.x;
    if (o >= 384 * 192) return;
    if (o < 384) {
        float bb = bq[o];
        if (o < 192) bb *= MULQ;
        ((float*)(wbf + 384 * 192))[o] = bb;
    }
    int e  = o & 7;
    int t  = o >> 3;
    int lr = t & 15;  t >>= 4;
    int lg = t & 3;   t >>= 2;
    int kk = t % 6;
    int ng = t / 6;
    int col  = ng * 16 + lr;
    int kcol = kk * 32 + lg * 8 + e;
    float wv = w[col * KDIM + kcol];
    if (col < 192) wv *= MULQ;            // q half pre-scaled
    __bf16 v = (__bf16)wv;
    wbf[o] = __builtin_bit_cast(uint16_t, v);
}

// 2 windows per block (4096 blocks), 1024 threads = 16 waves, 1 block/CU
// (16 waves/CU — R4==R10 showed this occupancy level is perf-neutral).
// Six distinct LDS buffers remove intra-window barriers:
//   B0 (gather both) -> GEMM1(w0) -> phase3(w0) -> B1 -> phase4(w0)
//   -> GEMM1(w1) -> phase3(w1) -> B2 -> phase4(w1)
// = 3 barriers / 2 windows (R16: 6). Phase-4 head imbalance fixed across
// the pair: w0's extra heads go to waves 0-7, w1's to waves 8-15 -> every
// wave does exactly 3 (head,qt) pairs; fast waves flow from phase4(w0)
// straight into GEMM1(w1) (X1 stable since B0; Q1/K1 disjoint from Q0/K0).
// No value lives across a barrier -> no spill at the 64-arch cap of (1024,4)
// (R5-R19: spill signature is FETCH/WRITE bloat, not VGPR_Count=64).
__global__ __launch_bounds__(1024, 4)
void attn_win2_kernel(const float* __restrict__ x,
                      const uint16_t* __restrict__ wbf,
                      float* __restrict__ out) {
    extern __shared__ char smem[];

    const int tid  = threadIdx.x;
    const int wave = tid >> 6;   // 0..15
    const int l    = tid & 63;
    const int lg   = l >> 4;     // 0..3
    const int lr   = l & 15;     // 0..15

    // XCD-bijective remap (4096 % 8 == 0): XCD i streams image i.
    const int blk  = (int)blockIdx.x;
    const int blk2 = (blk & 7) * (NBLK / 8) + (blk >> 3);
    const int wbase = blk2 * 2;              // 2 consecutive windows, same row
    const int b    = wbase >> 10;
    const int wh   = (wbase >> 5) & 31;
    const int ww0  = wbase & 31;             // even; ww0+1 <= 31
    const int h0   = wh * 7, w0p = ww0 * 7;

    const float* biasp = (const float*)(wbf + 384 * 192);
    const int mp = wave & 1;
    const int cg = wave >> 1;    // 0..7
    float bias0[3];
    #pragma unroll
    for (int nt = 0; nt < 3; ++nt)
        bias0[nt] = biasp[cg * 48 + nt * 16 + lr];

    const size_t HW2 = (size_t)HWD * HWD;

    // ---- Prologue: gather BOTH windows -> X0, X1.
    // lane = pixel (49 active), wave owns 12 channels; all 24 loads issued
    // back-to-back (one exposed latency), registers die before B0.
    if (l < NPIX) {
        int r = (l * 37) >> 8;          // l / 7 for l in [0,49)
        int s = l - r * 7;
        const float* xp = x + (size_t)(b * CCH + wave * 12) * HW2
                            + (size_t)(h0 + r) * HWD + (w0p + s);
        float g0[12], g1[12];
        #pragma unroll
        for (int c = 0; c < 12; ++c) g0[c] = xp[(size_t)c * HW2];
        #pragma unroll
        for (int c = 0; c < 12; ++c) g1[c] = xp[(size_t)c * HW2 + 7];
        const uint32_t rb  = (uint32_t)(l * ROWB + wave * 24);
        const uint32_t swz = (uint32_t)((l & 7) << 4);
        #pragma unroll
        for (int c = 0; c < 12; c += 2) {
            bf16x2 p0 = { (__bf16)g0[c], (__bf16)g0[c + 1] };
            bf16x2 p1 = { (__bf16)g1[c], (__bf16)g1[c + 1] };
            uint32_t byte = (rb + (uint32_t)(c * 2)) ^ swz;
            *(uint32_t*)(smem + X0O + byte) = __builtin_bit_cast(uint32_t, p0);
            *(uint32_t*)(smem + X1O + byte) = __builtin_bit_cast(uint32_t, p1);
        }
    }
    __syncthreads();   // B0: X0 and X1 ready

    // ---- GEMM1 + phase-3 staging for one window (acc is lambda-local,
    // never live across a barrier)
    auto gemm1_stage = [&](const char* xb, char* qb, char* kb) {
        f32x4 acc[2][3];
        #pragma unroll
        for (int nt = 0; nt < 3; ++nt) {
            float bb = bias0[nt];
            #pragma unroll
            for (int mt = 0; mt < 2; ++mt)
                acc[mt][nt] = f32x4{bb, bb, bb, bb};
        }
        #pragma unroll
        for (int kk = 0; kk < 6; ++kk) {
            bf16x8 afr[2];
            #pragma unroll
            for (int mt = 0; mt < 2; ++mt) {
                int row = mp * 32 + mt * 16 + lr;
                if (row > 48) row = 48;               // clamp: no pad rows
                int byte = (row * ROWB + kk * 64 + lg * 16) ^ ((row & 7) << 4);
                afr[mt] = *(const bf16x8*)(xb + byte);
            }
            bf16x8 bfr[3];
            #pragma unroll
            for (int nt = 0; nt < 3; ++nt)
                bfr[nt] = *(const bf16x8*)(
                    wbf + (((cg * 3 + nt) * 6 + kk) * 4 + lg) * 128 + lr * 8);
            #pragma unroll
            for (int nt = 0; nt < 3; ++nt)
                #pragma unroll
                for (int mt = 0; mt < 2; ++mt)
                    acc[mt][nt] = __builtin_amdgcn_mfma_f32_16x16x32_bf16(
                        afr[mt], bfr[nt], acc[mt][nt], 0, 0, 0);
        }
        // phase 3: q -> qb, k -> kb (bias/scale already in acc)
        const bool isq = (cg < 4);
        char* dst = isq ? qb : kb;
        #pragma unroll
        for (int nt = 0; nt < 3; ++nt) {
            int colW = cg * 48 + nt * 16 + lr;
            int jj = isq ? colW : (colW - 192);
            #pragma unroll
            for (int mt = 0; mt < 2; ++mt) {
                #pragma unroll
                for (int r = 0; r < 4; ++r) {
                    int row = mp * 32 + mt * 16 + lg * 4 + r;
                    if (row < NPIX) {
                        __bf16 bv = (__bf16)acc[mt][nt][r];
                        *(__bf16*)(dst +
                            ((row * ROWB + jj * 2) ^ ((row & 7) << 4))) = bv;
                    }
                }
            }
        }
    };

    // ---- phase-4 single (head, qt) pair
    const int qt    = wave & 3;
    const int qrow  = qt * 16 + lr;
    const int qrc   = qrow > 48 ? 48 : qrow;
    const uint32_t qswz = (uint32_t)((qrc & 7) << 4);
    const int h1 = wave >> 2;                // 0..3

    auto do_head = [&](int h, const char* qb, const char* kb, float* outw) {
        const bf16x8 qfr = *(const bf16x8*)(qb +
            (((uint32_t)(qrc * ROWB + h * 64 + lg * 16)) ^ qswz));

        float v[16];
        #pragma unroll
        for (int nt2 = 0; nt2 < 4; ++nt2) {
            int krow = nt2 * 16 + lr;
            if (krow > 48) krow = 48;                 // clamp (masked later)
            const bf16x8 kfr = *(const bf16x8*)(kb +
                (((uint32_t)(krow * ROWB + h * 64 + lg * 16)) ^ ((krow & 7) << 4)));
            f32x4 p = __builtin_amdgcn_mfma_f32_16x16x32_bf16(
                kfr, qfr, f32x4{0.f, 0.f, 0.f, 0.f}, 0, 0, 0);
            #pragma unroll
            for (int r = 0; r < 4; ++r) {
                int k = nt2 * 16 + lg * 4 + r;
                v[nt2 * 4 + r] = (k < NPIX) ? p[r] : -INFINITY;
            }
        }

        float m = v[0];
        #pragma unroll
        for (int i = 1; i < 16; ++i) m = fmaxf(m, v[i]);
        m = fmaxf(m, __shfl_xor(m, 16, 64));
        m = fmaxf(m, __shfl_xor(m, 32, 64));

        float sum = 0.f;
        #pragma unroll
        for (int i = 0; i < 16; ++i) {
            v[i] = exp2f(v[i] - m);    // logits already in log2 domain
            sum += v[i];
        }
        sum += __shfl_xor(sum, 16, 64);
        sum += __shfl_xor(sum, 32, 64);
        const float inv = __fdividef(1.0f, sum);

        if (qrow < NPIX) {
            float* orow = outw + h * (NPIX * NPIX) + qrow * NPIX;
            #pragma unroll
            for (int nt2 = 0; nt2 < 3; ++nt2)
                #pragma unroll
                for (int r = 0; r < 4; ++r)
                    orow[nt2 * 16 + lg * 4 + r] = v[nt2 * 4 + r] * inv;
            if (lg == 0) orow[48] = v[12] * inv;
        }
    };

    float* outw0 = out + (size_t)wbase * (NHEAD * NPIX * NPIX);
    float* outw1 = outw0 + (NHEAD * NPIX * NPIX);

    // ---- Window 0
    gemm1_stage(smem + X0O, smem + Q0O, smem + K0O);
    __syncthreads();   // B1: Q0/K0 visible
    do_head(h1, smem + Q0O, smem + K0O, outw0);
    if (wave < 8) do_head(h1 + 4, smem + Q0O, smem + K0O, outw0);

    // ---- Window 1 (no barrier: X1 stable since B0; Q1/K1 disjoint buffers)
    gemm1_stage(smem + X1O, smem + Q1O, smem + K1O);
    __syncthreads();   // B2: Q1/K1 visible (all waves already left phase4(w0))
    do_head(h1, smem + Q1O, smem + K1O, outw1);
    if (wave >= 8) do_head(h1 + 2, smem + Q1O, smem + K1O, outw1);
}

extern "C" void kernel_launch(void* const* d_in, const int* in_sizes, int n_in,
                              void* d_out, int out_size, void* d_ws, size_t ws_size,
                              hipStream_t stream) {
    const float* x  = (const float*)d_in[0];
    const float* W  = (const float*)d_in[1];
    const float* bq = (const float*)d_in[2];
    float* out = (float*)d_out;
    uint16_t* wbf = (uint16_t*)d_ws;   // 147456 B swizzled W + 1536 B bias f32

    wconv_kernel<<<(384 * 192 + 255) / 256, 256, 0, stream>>>(W, bq, wbf);
    attn_win2_kernel<<<NBLK, 1024, LDSSZ, stream>>>(x, wbf, out);
}

// Round 22
// 313.069 us; speedup vs baseline: 1.0267x; 1.0267x over previous
//
#include <hip/hip_runtime.h>
#include <hip/hip_bf16.h>
#include <math.h>
#include <stdint.h>

// Problem constants
#define CCH   192      // channels
#define HWD   224      // H = W = 224
#define NWIN  8192     // 8 * 32 * 32 windows
#define NPIX  49       // 7*7 pixels per window
#define KDIM  192      // GEMM1 K
#define NHEAD 6
#define ROWB  (KDIM * 2)   // 384 bytes per LDS row
#define MULQ  0.2550348616845977f   // 32^-0.5 * log2(e), folded into W_q/b_q

typedef __bf16 bf16x8 __attribute__((ext_vector_type(8)));
typedef __bf16 bf16x2 __attribute__((ext_vector_type(2)));
typedef float  f32x4  __attribute__((ext_vector_type(4)));

// Convert W (384x192 f32) to bf16 pre-swizzled into MFMA B-fragment order,
// with scale*log2e pre-folded into the q half (rows 0..191).
// out[((ng*6 + kk)*4 + lg)*128 + lr*8 + e] = W[(ng*16+lr)*192 + kk*32+lg*8+e]
// Also writes the (scaled) bias as f32 at wbf+73728.
__global__ void wconv_kernel(const float* __restrict__ w,
                             const float* __restrict__ bq,
                             uint16_t* __restrict__ wbf) {
    int o = blockIdx.x * 256 + threadIdx.x;
    if (o >= 384 * 192) return;
    if (o < 384) {
        float bb = bq[o];
        if (o < 192) bb *= MULQ;
        ((float*)(wbf + 384 * 192))[o] = bb;
    }
    int e  = o & 7;
    int t  = o >> 3;
    int lr = t & 15;  t >>= 4;
    int lg = t & 3;   t >>= 2;
    int kk = t % 6;
    int ng = t / 6;
    int col  = ng * 16 + lr;
    int kcol = kk * 32 + lg * 8 + e;
    float wv = w[col * KDIM + kcol];
    if (col < 192) wv *= MULQ;            // q half pre-scaled
    __bf16 v = (__bf16)wv;
    wbf[o] = __builtin_bit_cast(uint16_t, v);
}

// FINAL KERNEL — one block per window, 1024 threads = 16 waves, 2 blocks/CU
// (32 waves/CU). Best verified: 313.5 us scored (R16, reproduced R20).
// Session findings baked in:
// - unified reg file splits ~evenly VGPR/AGPR; arch cap = wave budget / 2.
//   At (1024,8): 32 arch regs. This kernel fits exactly; ANY value held
//   live across a barrier spills (R5/R6/R9/R13/R15/R17/R19 confirmed).
// - 2nd resident block/CU is worth ~7% (R16 vs R21); beyond that flat (R10).
// - softmax is free (R14 ablation: V0 == V2); phases are additive.
// - register prefetch, global_load_lds DMA (12x FETCH on 4B scatter), LDS
//   panel staging, batched multi-window gather: all regress. The remaining
//   gap to the 124us HBM floor is gather/W-load latency that cannot be
//   hidden within this problem's register/LDS/coalescing constraints.
__global__ __launch_bounds__(1024, 8)
void attn_win_kernel(const float* __restrict__ x,
                     const uint16_t* __restrict__ wbf,
                     float* __restrict__ out) {
    __shared__ uint16_t ldsA[NPIX * KDIM];   // xw tile, later q
    __shared__ uint16_t ldsB[NPIX * KDIM];   // k

    const int tid  = threadIdx.x;
    const int wave = tid >> 6;   // 0..15
    const int l    = tid & 63;
    const int lg   = l >> 4;     // 0..3
    const int lr   = l & 15;     // 0..15

    // XCD-bijective remap: each XCD gets one contiguous batch image (8192 % 8 == 0)
    const int win = ((blockIdx.x & 7) << 10) | (blockIdx.x >> 3);
    const int b   = win >> 10;
    const int wh  = (win >> 5) & 31;
    const int ww  = win & 31;
    const int h0 = wh * 7, w0 = ww * 7;

    const float* bias = (const float*)(wbf + 384 * 192);

    // ---- Phase 1: gather x window -> ldsA (bf16, XOR-swizzled rows).
    // lane = pixel (49 active), wave owns 12 channels. All 12 loads issued
    // before any LDS write (single exposed HBM latency; regs are phase-local).
    if (l < NPIX) {
        int r = (l * 37) >> 8;          // l / 7 for l in [0,49)
        int s = l - r * 7;
        const float* xp = x + (size_t)(b * CCH + wave * 12) * (HWD * HWD)
                            + (h0 + r) * HWD + (w0 + s);
        float g[12];
        #pragma unroll
        for (int c = 0; c < 12; ++c)
            g[c] = xp[(size_t)c * (HWD * HWD)];
        const uint32_t rb  = (uint32_t)(l * ROWB + wave * 24);
        const uint32_t swz = (uint32_t)((l & 7) << 4);
        #pragma unroll
        for (int c = 0; c < 12; c += 2) {
            bf16x2 p = { (__bf16)g[c], (__bf16)g[c + 1] };
            uint32_t byte = (rb + (uint32_t)(c * 2)) ^ swz;
            *(uint32_t*)((char*)ldsA + byte) = __builtin_bit_cast(uint32_t, p);
        }
    }
    __syncthreads();

    // ---- Phase 2: GEMM1  qk[64 x 384] = xw @ W^T (+bias via acc init)
    // wave = (mp, cg): rows mp*32..mp*32+31, cols cg*48..cg*48+47.
    const int mp = wave & 1;
    const int cg = wave >> 1;    // 0..7
    f32x4 acc[2][3];
    #pragma unroll
    for (int nt = 0; nt < 3; ++nt) {
        float bb = bias[cg * 48 + nt * 16 + lr];   // col = lr across all 4 regs
        #pragma unroll
        for (int mt = 0; mt < 2; ++mt)
            acc[mt][nt] = f32x4{bb, bb, bb, bb};
    }

    #pragma unroll
    for (int kk = 0; kk < 6; ++kk) {
        bf16x8 afr[2];
        #pragma unroll
        for (int mt = 0; mt < 2; ++mt) {
            int row = mp * 32 + mt * 16 + lr;
            if (row > 48) row = 48;                       // clamp: no pad rows
            int byte = (row * ROWB + kk * 64 + lg * 16) ^ ((row & 7) << 4);
            afr[mt] = *(const bf16x8*)((const char*)ldsA + byte);
        }
        // batch the 3 B-fragment loads (independent, issue back-to-back)
        bf16x8 bfr[3];
        #pragma unroll
        for (int nt = 0; nt < 3; ++nt)
            bfr[nt] = *(const bf16x8*)(
                wbf + (((cg * 3 + nt) * 6 + kk) * 4 + lg) * 128 + lr * 8);
        #pragma unroll
        for (int nt = 0; nt < 3; ++nt)
            #pragma unroll
            for (int mt = 0; mt < 2; ++mt)
                acc[mt][nt] = __builtin_amdgcn_mfma_f32_16x16x32_bf16(
                    afr[mt], bfr[nt], acc[mt][nt], 0, 0, 0);
    }
    __syncthreads();   // all GEMM1 reads of ldsA done before q overwrites it

    // ---- Phase 3: q -> ldsA, k -> ldsB (bf16); bias/scale already applied
    {
        const bool isq = (cg < 4);
        uint16_t* dst = isq ? ldsA : ldsB;
        #pragma unroll
        for (int nt = 0; nt < 3; ++nt) {
            int colW = cg * 48 + nt * 16 + lr;    // 0..383
            int jj = isq ? colW : (colW - 192);
            #pragma unroll
            for (int mt = 0; mt < 2; ++mt) {
                #pragma unroll
                for (int r = 0; r < 4; ++r) {
                    int row = mp * 32 + mt * 16 + lg * 4 + r;
                    if (row < NPIX) {
                        __bf16 bv = (__bf16)acc[mt][nt][r];
                        *(__bf16*)((char*)dst +
                            ((row * ROWB + jj * 2) ^ ((row & 7) << 4))) = bv;
                    }
                }
            }
        }
    }
    __syncthreads();

    // ---- Phase 4: swapped-operand GEMM2 + lane-local softmax + direct stores.
    // mfma(K_tile, Q_tile): D col = q-row, D row = k-idx. Lane (lg,lr) of wave
    // (qt = wave&3) holds S[qrow = qt*16+lr][k = nt2*16 + lg*4 + r].
    // 24 (head,qt) pairs over 16 waves: wave w does head w>>2 (0..3), and
    // waves 0-7 also do head (w>>2)+4.
    float* outw = out + (size_t)win * (NHEAD * NPIX * NPIX);
    const int qt    = wave & 3;
    const int qrow  = qt * 16 + lr;
    const int qrc   = qrow > 48 ? 48 : qrow;            // clamped read row
    const uint32_t qswz = (uint32_t)((qrc & 7) << 4);

    auto do_head = [&](int h) {
        const bf16x8 qfr = *(const bf16x8*)((const char*)ldsA +
            (((uint32_t)(qrc * ROWB + h * 64 + lg * 16)) ^ qswz));

        float v[16];
        #pragma unroll
        for (int nt2 = 0; nt2 < 4; ++nt2) {
            int krow = nt2 * 16 + lr;
            if (krow > 48) krow = 48;                   // clamp (masked later)
            const bf16x8 kfr = *(const bf16x8*)((const char*)ldsB +
                (((uint32_t)(krow * ROWB + h * 64 + lg * 16)) ^ ((krow & 7) << 4)));
            f32x4 p = __builtin_amdgcn_mfma_f32_16x16x32_bf16(
                kfr, qfr, f32x4{0.f, 0.f, 0.f, 0.f}, 0, 0, 0);
            #pragma unroll
            for (int r = 0; r < 4; ++r) {
                int k = nt2 * 16 + lg * 4 + r;
                v[nt2 * 4 + r] = (k < NPIX) ? p[r] : -INFINITY;
            }
        }

        // row softmax: 16 in-lane values + 2 cross-lane steps (l^16, l^32)
        float m = v[0];
        #pragma unroll
        for (int i = 1; i < 16; ++i) m = fmaxf(m, v[i]);
        m = fmaxf(m, __shfl_xor(m, 16, 64));
        m = fmaxf(m, __shfl_xor(m, 32, 64));

        float sum = 0.f;
        #pragma unroll
        for (int i = 0; i < 16; ++i) {
            v[i] = exp2f(v[i] - m);    // logits already in log2 domain
            sum += v[i];
        }
        sum += __shfl_xor(sum, 16, 64);
        sum += __shfl_xor(sum, 32, 64);
        const float inv = __fdividef(1.0f, sum);

        if (qrow < NPIX) {
            float* orow = outw + h * (NPIX * NPIX) + qrow * NPIX;
            #pragma unroll
            for (int nt2 = 0; nt2 < 3; ++nt2)
                #pragma unroll
                for (int r = 0; r < 4; ++r)
                    orow[nt2 * 16 + lg * 4 + r] = v[nt2 * 4 + r] * inv;
            if (lg == 0) orow[48] = v[12] * inv;
        }
    };

    const int h1 = wave >> 2;      // 0..3
    do_head(h1);
    if (wave < 8) do_head(h1 + 4); // heads 4,5
}

extern "C" void kernel_launch(void* const* d_in, const int* in_sizes, int n_in,
                              void* d_out, int out_size, void* d_ws, size_t ws_size,
                              hipStream_t stream) {
    const float* x  = (const float*)d_in[0];
    const float* W  = (const float*)d_in[1];
    const float* bq = (const float*)d_in[2];
    float* out = (float*)d_out;
    uint16_t* wbf = (uint16_t*)d_ws;   // 147456 B swizzled W + 1536 B bias f32

    wconv_kernel<<<(384 * 192 + 255) / 256, 256, 0, stream>>>(W, bq, wbf);
    attn_win_kernel<<<NWIN, 1024, 0, stream>>>(x, wbf, out);
}